// Round 7
// baseline (340.402 us; speedup 1.0000x reference)
//
#include <hip/hip_runtime.h>
#include <math.h>

// Model: B=32, C=64, T=1024, H=10, OUT=2.
// ONE kernel, 32 blocks (one per batch element) x 1024 threads (one per t).
// S1 embed | S2 bn+tanh (+qkv stats on the fly) | S3 recompute qkv -> act +
// per-b M=KV^T | S4 N=M Wc^T/H, prec=q.N | S5 bn+relu -> Iin into LDS |
// S6 LSNN scan on wave 0 from LDS (ballot spike broadcast, analytic LI wts).
// Cross-block: BN batch stats (3x) via agent-scope atomics + 32-block barrier.
//
// R6 post-mortem: VGPR pinned at 64 because the backend targets the max
// HW-schedulable occupancy (2 blocks/CU from 55.8KB LDS => 8 waves/EU =>
// 512/8 = 64 VGPRs) and __launch_bounds__'s 2nd arg is only a MINIMUM.
// Result: ~900B/thread scratch spill = 28.8 MB WRITE_SIZE. R7 fix:
// amdgpu_waves_per_eu(4,4) pins the target at 4 waves/EU (1 block/CU --
// all we can use with grid=32 anyway) => 128-VGPR budget, no spills.

constexpr int B = 32, C = 64, T = 1024, H = 10;

struct Params {
  const float *beeg, *W_ef, *b_ef, *g_i, *be_i, *Wq, *g_q, *be_q, *Wk, *g_k,
      *be_k, *Wv, *g_v, *be_v, *Wc, *g_c, *be_c, *W_in, *W_rec, *W_cls, *b_cls;
  int* cnt;              // barrier counters (memset 0 each launch)
  double *P1, *P2, *P3;  // cross-block stat partials
  float* out;
};

__device__ inline float wred(float v) {
#pragma unroll
  for (int o = 32; o; o >>= 1) v += __shfl_down(v, o, 64);
  return v;
}

// 32-block device-scope barrier (release/acquire on counter orders partials).
__device__ inline void gbar(int* cnt, int phase, int tid) {
  __syncthreads();
  if (tid == 0) {
    __threadfence();
    __hip_atomic_fetch_add(&cnt[phase], 1, __ATOMIC_RELEASE,
                           __HIP_MEMORY_SCOPE_AGENT);
    while (__hip_atomic_load(&cnt[phase], __ATOMIC_ACQUIRE,
                             __HIP_MEMORY_SCOPE_AGENT) < B)
      __builtin_amdgcn_s_sleep(1);
    __threadfence();
  }
  __syncthreads();
}

// wlds layout (floats)
#define WEF 0      // 640: W_ef
#define WQ  640    // 100
#define WK  740    // 100
#define WV  840    // 100
#define WC  940    // 100
#define WIN 1040   // 100
#define GI  1140
#define BEI 1150
#define GQ  1160
#define BEQ 1170
#define GK  1180
#define BEK 1190
#define GV  1200
#define BEV 1210
#define GC  1220
#define BEC 1230
#define BEF 1240   // 10

__global__ void __launch_bounds__(1024)
__attribute__((amdgpu_waves_per_eu(4, 4)))
fused4(Params p) {
  const int b = blockIdx.x, tid = threadIdx.x;
  const int lane = tid & 63, wid = tid >> 6;   // 16 waves
  const int t = tid;

  __shared__ __align__(16) float slab[T * 11];  // 45056 B: scratch then Iin
  __shared__ __align__(16) float gtab[T];       // 4 KB
  __shared__ float wlds[1250 + 16];             // staged weights/params
  __shared__ double dtot[60];
  __shared__ float stM[30], stI[30], Ms[100], Nl[100];

  float* swred = slab;         // [16][60] stats scratch
  float* mpw   = slab + 960;   // [16][100] M partials

  // ---------------- stage all small weights into LDS
  for (int i = tid; i < 640; i += 1024) wlds[WEF + i] = p.W_ef[i];
  if (tid < 100) {
    wlds[WQ + tid]  = p.Wq[tid];
    wlds[WK + tid]  = p.Wk[tid];
    wlds[WV + tid]  = p.Wv[tid];
    wlds[WC + tid]  = p.Wc[tid];
    wlds[WIN + tid] = p.W_in[tid];
  }
  if (tid < 10) {
    wlds[GI + tid]  = p.g_i[tid];  wlds[BEI + tid] = p.be_i[tid];
    wlds[GQ + tid]  = p.g_q[tid];  wlds[BEQ + tid] = p.be_q[tid];
    wlds[GK + tid]  = p.g_k[tid];  wlds[BEK + tid] = p.be_k[tid];
    wlds[GV + tid]  = p.g_v[tid];  wlds[BEV + tid] = p.be_v[tid];
    wlds[GC + tid]  = p.g_c[tid];  wlds[BEC + tid] = p.be_c[tid];
    wlds[BEF + tid] = p.b_ef[tid];
  }
  __syncthreads();

  // ---------------- S1: embed
  float pre1[H];
#pragma unroll
  for (int h = 0; h < H; ++h) pre1[h] = wlds[BEF + h];
  {
    const float* bp = p.beeg + (size_t)b * C * T + t;
    for (int c = 0; c < C; ++c) {
      float x = bp[(size_t)c * T];
#pragma unroll
      for (int h = 0; h < H; ++h)
        pre1[h] = fmaf(x, wlds[WEF + h * C + c], pre1[h]);
    }
  }
#pragma unroll
  for (int h = 0; h < H; ++h) {
    float r1 = wred(pre1[h]), r2 = wred(pre1[h] * pre1[h]);
    if (lane == 0) { swred[wid * 60 + h] = r1; swred[wid * 60 + 10 + h] = r2; }
  }
  __syncthreads();
  if (tid < 20) {
    double s = 0.0;
#pragma unroll
    for (int w = 0; w < 16; ++w) s += (double)swred[w * 60 + tid];
    __hip_atomic_store(&p.P1[b * 20 + tid], s, __ATOMIC_RELAXED,
                       __HIP_MEMORY_SCOPE_AGENT);
  }
  gbar(p.cnt, 0, tid);
  if (tid < 20) {
    double s = 0.0;
    for (int i = 0; i < B; ++i)
      s += __hip_atomic_load(&p.P1[i * 20 + tid], __ATOMIC_RELAXED,
                             __HIP_MEMORY_SCOPE_AGENT);
    dtot[tid] = s;
  }
  __syncthreads();
  if (tid < 10) {
    double mean = dtot[tid] * (1.0 / 32768.0);
    double var  = dtot[10 + tid] * (1.0 / 32768.0) - mean * mean;
    stM[tid] = (float)mean;
    stI[tid] = (float)(1.0 / sqrt(var + 1e-5));
  }
  __syncthreads();

  // ---------------- S2: x = tanh(bn(pre1)); qkv stats ON THE FLY (no carry)
  float x[H];
#pragma unroll
  for (int j = 0; j < H; ++j)
    x[j] = tanhf(wlds[GI + j] * (pre1[j] - stM[j]) * stI[j] + wlds[BEI + j]);
  // pre1 dead now; only x[10] persists across the next barrier.
#pragma unroll
  for (int h = 0; h < H; ++h) {
    float a_q = 0.f, a_k = 0.f, a_v = 0.f;
#pragma unroll
    for (int j = 0; j < H; ++j) {
      a_q = fmaf(x[j], wlds[WQ + h * H + j], a_q);
      a_k = fmaf(x[j], wlds[WK + h * H + j], a_k);
      a_v = fmaf(x[j], wlds[WV + h * H + j], a_v);
    }
    float r1 = wred(a_q), r2 = wred(a_q * a_q);
    float r3 = wred(a_k), r4 = wred(a_k * a_k);
    float r5 = wred(a_v), r6 = wred(a_v * a_v);
    if (lane == 0) {
      swred[wid * 60 + h]      = r1; swred[wid * 60 + 30 + h] = r2;
      swred[wid * 60 + 10 + h] = r3; swred[wid * 60 + 40 + h] = r4;
      swred[wid * 60 + 20 + h] = r5; swred[wid * 60 + 50 + h] = r6;
    }
  }
  __syncthreads();
  if (tid < 60) {
    double s = 0.0;
#pragma unroll
    for (int w = 0; w < 16; ++w) s += (double)swred[w * 60 + tid];
    __hip_atomic_store(&p.P2[b * 60 + tid], s, __ATOMIC_RELAXED,
                       __HIP_MEMORY_SCOPE_AGENT);
  }
  gbar(p.cnt, 1, tid);
  if (tid < 60) {
    double s = 0.0;
    for (int i = 0; i < B; ++i)
      s += __hip_atomic_load(&p.P2[i * 60 + tid], __ATOMIC_RELAXED,
                             __HIP_MEMORY_SCOPE_AGENT);
    dtot[tid] = s;
  }
  __syncthreads();
  if (tid < 30) {
    double mean = dtot[tid] * (1.0 / 32768.0);
    double var  = dtot[30 + tid] * (1.0 / 32768.0) - mean * mean;
    stM[tid] = (float)mean;
    stI[tid] = (float)(1.0 / sqrt(var + 1e-5));
  }
  __syncthreads();

  // ---------------- S3: recompute qkv pre-acts -> activations; per-b M
  float qv[H], kx[H], vx[H];
#pragma unroll
  for (int h = 0; h < H; ++h) {
    float a_q = 0.f, a_k = 0.f, a_v = 0.f;
#pragma unroll
    for (int j = 0; j < H; ++j) {
      a_q = fmaf(x[j], wlds[WQ + h * H + j], a_q);
      a_k = fmaf(x[j], wlds[WK + h * H + j], a_k);
      a_v = fmaf(x[j], wlds[WV + h * H + j], a_v);
    }
    qv[h] = fmaxf(wlds[GQ + h] * (a_q - stM[h])      * stI[h]      + wlds[BEQ + h], 0.f);
    kx[h] = fmaxf(wlds[GK + h] * (a_k - stM[10 + h]) * stI[10 + h] + wlds[BEK + h], 0.f);
    vx[h] = tanhf(wlds[GV + h] * (a_v - stM[20 + h]) * stI[20 + h] + wlds[BEV + h]);
  }
  // x dead now. M partials, fully unrolled (no runtime private indexing).
#pragma unroll
  for (int i = 0; i < H; ++i)
#pragma unroll
    for (int j = 0; j < H; ++j) {
      float r = wred(kx[i] * vx[j]);
      if (lane == 0) mpw[wid * 100 + i * 10 + j] = r;
    }
  __syncthreads();
  if (tid < 100) {
    float s = 0.f;
#pragma unroll
    for (int w = 0; w < 16; ++w) s += mpw[w * 100 + tid];
    Ms[tid] = s;
  }
  __syncthreads();

  // ---------------- S4: N = (M Wc^T)/H, prec = q . N
  if (tid < 100) {
    int i = tid / 10, h = tid % 10;
    float a = 0.f;
#pragma unroll
    for (int j = 0; j < H; ++j) a = fmaf(Ms[i * 10 + j], wlds[WC + h * H + j], a);
    Nl[tid] = a * 0.1f;
  }
  __syncthreads();
  float prec[H];
#pragma unroll
  for (int h = 0; h < H; ++h) {
    float a = 0.f;
#pragma unroll
    for (int i = 0; i < H; ++i) a = fmaf(qv[i], Nl[i * 10 + h], a);
    prec[h] = a;
  }
#pragma unroll
  for (int h = 0; h < H; ++h) {
    float r1 = wred(prec[h]), r2 = wred(prec[h] * prec[h]);
    if (lane == 0) { swred[wid * 60 + h] = r1; swred[wid * 60 + 10 + h] = r2; }
  }
  __syncthreads();
  if (tid < 20) {
    double s = 0.0;
#pragma unroll
    for (int w = 0; w < 16; ++w) s += (double)swred[w * 60 + tid];
    __hip_atomic_store(&p.P3[b * 20 + tid], s, __ATOMIC_RELAXED,
                       __HIP_MEMORY_SCOPE_AGENT);
  }
  gbar(p.cnt, 2, tid);
  if (tid < 20) {
    double s = 0.0;
    for (int i = 0; i < B; ++i)
      s += __hip_atomic_load(&p.P3[i * 20 + tid], __ATOMIC_RELAXED,
                             __HIP_MEMORY_SCOPE_AGENT);
    dtot[tid] = s;
  }
  __syncthreads();
  if (tid < 10) {
    double mean = dtot[tid] * (1.0 / 32768.0);
    double var  = dtot[10 + tid] * (1.0 / 32768.0) - mean * mean;
    stM[tid] = (float)mean;
    stI[tid] = (float)(1.0 / sqrt(var + 1e-5));
  }
  __syncthreads();   // all slab-scratch reads done before S5 overwrites

  // ---------------- S5: bn+relu, Iin into LDS slab (stride 11); f32 g-table
  {
    float xc[H];
#pragma unroll
    for (int j = 0; j < H; ++j)
      xc[j] = fmaxf(wlds[GC + j] * (prec[j] - stM[j]) * stI[j] + wlds[BEC + j], 0.f);
#pragma unroll
    for (int h = 0; h < H; ++h) {
      float a = 0.f;
#pragma unroll
      for (int j = 0; j < H; ++j) a = fmaf(xc[j], wlds[WIN + h * H + j], a);
      slab[t * 11 + h] = a;
    }
    // g[t] = c*(Ga-Gd)/(a-d)/T with a=0.9,d=0.8,c=0.1 => (9(1-pa)-4(1-pd))/T
    const float L2A = -0.15200309344504995f;   // log2(0.9)
    const float L2D = -0.32192809488736235f;   // log2(0.8)
    float m1 = (float)(T - t);                 // Mi+1
    float pa = exp2f(m1 * L2A), pd = exp2f(m1 * L2D);
    gtab[t] = (9.0f * (1.0f - pa) - 4.0f * (1.0f - pd)) * (1.0f / (float)T);
  }
  __syncthreads();

  // ---------------- S6: LSNN scan, wave 0 only, from LDS
  if (tid < 64) {
    float gs = 0.f;
#pragma unroll
    for (int i = 0; i < 16; ++i) gs += gtab[lane + 64 * i];
    float gtot = __shfl(wred(gs), 0, 64);

    const int slot = lane < H ? lane : 0;   // inactive lanes broadcast slot 0
    float wr[H];
#pragma unroll
    for (int j = 0; j < H; ++j)
      wr[j] = (lane < H) ? p.W_rec[lane * H + j] : 0.f;

    float cur = 0.f, vm = 0.f, S = 0.f;
    unsigned zm = 0u;

    auto step = [&](float iin, float gt) {
      float p01 = (((zm >> 0) & 1u) ? wr[0] : 0.f) + (((zm >> 1) & 1u) ? wr[1] : 0.f);
      float p23 = (((zm >> 2) & 1u) ? wr[2] : 0.f) + (((zm >> 3) & 1u) ? wr[3] : 0.f);
      float p45 = (((zm >> 4) & 1u) ? wr[4] : 0.f) + (((zm >> 5) & 1u) ? wr[5] : 0.f);
      float p67 = (((zm >> 6) & 1u) ? wr[6] : 0.f) + (((zm >> 7) & 1u) ? wr[7] : 0.f);
      float p89 = (((zm >> 8) & 1u) ? wr[8] : 0.f) + (((zm >> 9) & 1u) ? wr[9] : 0.f);
      float rec = ((p01 + p23) + (p45 + p67)) + p89;
      float i_jump = (cur + iin) + rec;
      float v_dec = fmaf(0.1f, i_jump - vm, vm);  // vm + 0.1*(i_jump - vm)
      cur = 0.8f * i_jump;                        // i_dec
      bool z = v_dec > 0.5f;
      vm = z ? 0.f : v_dec;
      S += z ? gt : 0.f;
      zm = (unsigned)__ballot(z) & 0x3FFu;
    };

    float ibuf[8];
#pragma unroll
    for (int u = 0; u < 8; ++u) ibuf[u] = slab[u * 11 + slot];
    float4 gA = *(const float4*)&gtab[0], gB = *(const float4*)&gtab[4];

    for (int t8 = 0; t8 < T - 8; t8 += 8) {
      float4 nA = *(const float4*)&gtab[t8 + 8];
      float4 nB = *(const float4*)&gtab[t8 + 12];
      step(ibuf[0], gA.x); ibuf[0] = slab[(t8 +  8) * 11 + slot];
      step(ibuf[1], gA.y); ibuf[1] = slab[(t8 +  9) * 11 + slot];
      step(ibuf[2], gA.z); ibuf[2] = slab[(t8 + 10) * 11 + slot];
      step(ibuf[3], gA.w); ibuf[3] = slab[(t8 + 11) * 11 + slot];
      step(ibuf[4], gB.x); ibuf[4] = slab[(t8 + 12) * 11 + slot];
      step(ibuf[5], gB.y); ibuf[5] = slab[(t8 + 13) * 11 + slot];
      step(ibuf[6], gB.z); ibuf[6] = slab[(t8 + 14) * 11 + slot];
      step(ibuf[7], gB.w); ibuf[7] = slab[(t8 + 15) * 11 + slot];
      gA = nA; gB = nB;
    }
    step(ibuf[0], gA.x); step(ibuf[1], gA.y);
    step(ibuf[2], gA.z); step(ibuf[3], gA.w);
    step(ibuf[4], gB.x); step(ibuf[5], gB.y);
    step(ibuf[6], gB.z); step(ibuf[7], gB.w);

    int li = lane < H ? lane : 0;
    float c0 = (lane < H) ? S * p.W_cls[li]     : 0.f;
    float c1 = (lane < H) ? S * p.W_cls[H + li] : 0.f;
    float r0 = wred(c0), r1 = wred(c1);
    if (lane == 0) {
      p.out[b * 2 + 0] = r0 + gtot * p.b_cls[0];
      p.out[b * 2 + 1] = r1 + gtot * p.b_cls[1];
    }
  }
}

extern "C" void kernel_launch(void* const* d_in, const int* in_sizes, int n_in,
                              void* d_out, int out_size, void* d_ws, size_t ws_size,
                              hipStream_t stream) {
  Params p;
  p.beeg  = (const float*)d_in[2];
  p.W_ef  = (const float*)d_in[4];
  p.b_ef  = (const float*)d_in[5];
  p.g_i   = (const float*)d_in[6];
  p.be_i  = (const float*)d_in[7];
  p.Wq    = (const float*)d_in[8];
  p.g_q   = (const float*)d_in[9];
  p.be_q  = (const float*)d_in[10];
  p.Wk    = (const float*)d_in[11];
  p.g_k   = (const float*)d_in[12];
  p.be_k  = (const float*)d_in[13];
  p.Wv    = (const float*)d_in[14];
  p.g_v   = (const float*)d_in[15];
  p.be_v  = (const float*)d_in[16];
  p.Wc    = (const float*)d_in[17];
  p.g_c   = (const float*)d_in[18];
  p.be_c  = (const float*)d_in[19];
  p.W_in  = (const float*)d_in[20];
  p.W_rec = (const float*)d_in[21];
  p.W_cls = (const float*)d_in[22];
  p.b_cls = (const float*)d_in[23];

  char* ws = (char*)d_ws;
  p.cnt = (int*)ws;                            // 3 counters, memset below
  p.P1  = (double*)(ws + 256);                 // 32*20 doubles
  p.P2  = (double*)(ws + 256 + 5120);          // 32*60 doubles
  p.P3  = (double*)(ws + 256 + 5120 + 15360);  // 32*20 doubles
  p.out = (float*)d_out;

  hipMemsetAsync(d_ws, 0, 256, stream);   // zero barrier counters (capturable)
  fused4<<<dim3(B), dim3(1024), 0, stream>>>(p);
}

// Round 8
// 300.606 us; speedup vs baseline: 1.1324x; 1.1324x over previous
//
#include <hip/hip_runtime.h>
#include <math.h>

// Model: B=32, C=64, T=1024, H=10, OUT=2.
// ONE kernel, 32 blocks (one per batch element) x 512 threads; each thread
// owns TWO time-steps (t, t+512). S1 embed | S2 bn+tanh (+qkv stats on the
// fly) | S3 recompute qkv -> act + per-b M=KV^T | S4 N=M Wc^T/H, prec=q.N |
// S5 bn+relu -> Iin into LDS | S6 LSNN scan on wave 0 from LDS.
// Cross-block: BN batch stats (3x) via agent-scope atomics + 32-block barrier.
//
// R4-R7 post-mortem: with 1024-thread blocks the backend's register budget
// is set by compile-time occupancy-by-LDS: 55.8KB LDS -> 2 WGs/CU -> 32
// waves/CU -> 8 waves/SIMD -> 64 VGPRs, causing ~880B/thread scratch spill
// (28.8MB WRITE_SIZE). launch_bounds 2nd arg and amdgpu_waves_per_eu were
// both ignored. R8: 512-thread blocks make the SAME heuristic yield
// 2 WGs x 8 waves = 16 waves/CU = 4 waves/SIMD -> 128-VGPR budget.
// Peak live ~100 VGPRs -> no spills, by construction of the heuristic.

constexpr int B = 32, C = 64, T = 1024, H = 10;
constexpr int NT = 512;   // threads per block (8 waves)

struct Params {
  const float *beeg, *W_ef, *b_ef, *g_i, *be_i, *Wq, *g_q, *be_q, *Wk, *g_k,
      *be_k, *Wv, *g_v, *be_v, *Wc, *g_c, *be_c, *W_in, *W_rec, *W_cls, *b_cls;
  int* cnt;              // barrier counters (memset 0 each launch)
  double *P1, *P2, *P3;  // cross-block stat partials
  float* out;
};

__device__ inline float wred(float v) {
#pragma unroll
  for (int o = 32; o; o >>= 1) v += __shfl_down(v, o, 64);
  return v;
}

// 32-block device-scope barrier (release/acquire on counter orders partials).
__device__ inline void gbar(int* cnt, int phase, int tid) {
  __syncthreads();
  if (tid == 0) {
    __threadfence();
    __hip_atomic_fetch_add(&cnt[phase], 1, __ATOMIC_RELEASE,
                           __HIP_MEMORY_SCOPE_AGENT);
    while (__hip_atomic_load(&cnt[phase], __ATOMIC_ACQUIRE,
                             __HIP_MEMORY_SCOPE_AGENT) < B)
      __builtin_amdgcn_s_sleep(1);
    __threadfence();
  }
  __syncthreads();
}

// wlds layout (floats)
#define WEF 0      // 640: W_ef
#define WQ  640    // 100
#define WK  740    // 100
#define WV  840    // 100
#define WC  940    // 100
#define WIN 1040   // 100
#define GI  1140
#define BEI 1150
#define GQ  1160
#define BEQ 1170
#define GK  1180
#define BEK 1190
#define GV  1200
#define BEV 1210
#define GC  1220
#define BEC 1230
#define BEF 1240   // 10

__global__ void __launch_bounds__(NT) fused5(Params p) {
  const int b = blockIdx.x, tid = threadIdx.x;
  const int lane = tid & 63, wid = tid >> 6;   // 8 waves
  const int t0 = tid, t1 = tid + NT;

  __shared__ __align__(16) float slab[T * 11];  // 45056 B: scratch then Iin
  __shared__ __align__(16) float gtab[T];       // 4 KB
  __shared__ float wlds[1250 + 16];             // staged weights/params
  __shared__ double dtot[60];
  __shared__ float stM[30], stI[30], Ms[100], Nl[100];

  float* swred = slab;         // [8][60] stats scratch (dead before S5)
  float* mpw   = slab + 512;   // [8][100] M partials

  // ---------------- stage all small weights into LDS
  for (int i = tid; i < 640; i += NT) wlds[WEF + i] = p.W_ef[i];
  if (tid < 100) {
    wlds[WQ + tid]  = p.Wq[tid];
    wlds[WK + tid]  = p.Wk[tid];
    wlds[WV + tid]  = p.Wv[tid];
    wlds[WC + tid]  = p.Wc[tid];
    wlds[WIN + tid] = p.W_in[tid];
  }
  if (tid < 10) {
    wlds[GI + tid]  = p.g_i[tid];  wlds[BEI + tid] = p.be_i[tid];
    wlds[GQ + tid]  = p.g_q[tid];  wlds[BEQ + tid] = p.be_q[tid];
    wlds[GK + tid]  = p.g_k[tid];  wlds[BEK + tid] = p.be_k[tid];
    wlds[GV + tid]  = p.g_v[tid];  wlds[BEV + tid] = p.be_v[tid];
    wlds[GC + tid]  = p.g_c[tid];  wlds[BEC + tid] = p.be_c[tid];
    wlds[BEF + tid] = p.b_ef[tid];
  }
  __syncthreads();

  // ---------------- S1: embed (two t's per thread)
  float p1a[H], p1b[H];
#pragma unroll
  for (int h = 0; h < H; ++h) { p1a[h] = wlds[BEF + h]; p1b[h] = wlds[BEF + h]; }
  {
    const float* bp = p.beeg + (size_t)b * C * T;
    for (int c = 0; c < C; ++c) {
      float xa = bp[(size_t)c * T + t0];
      float xb = bp[(size_t)c * T + t1];
#pragma unroll
      for (int h = 0; h < H; ++h) {
        float w = wlds[WEF + h * C + c];
        p1a[h] = fmaf(xa, w, p1a[h]);
        p1b[h] = fmaf(xb, w, p1b[h]);
      }
    }
  }
#pragma unroll
  for (int h = 0; h < H; ++h) {
    float r1 = wred(p1a[h] + p1b[h]);
    float r2 = wred(p1a[h] * p1a[h] + p1b[h] * p1b[h]);
    if (lane == 0) { swred[wid * 60 + h] = r1; swred[wid * 60 + 10 + h] = r2; }
  }
  __syncthreads();
  if (tid < 20) {
    double s = 0.0;
#pragma unroll
    for (int w = 0; w < 8; ++w) s += (double)swred[w * 60 + tid];
    __hip_atomic_store(&p.P1[b * 20 + tid], s, __ATOMIC_RELAXED,
                       __HIP_MEMORY_SCOPE_AGENT);
  }
  gbar(p.cnt, 0, tid);
  if (tid < 20) {
    double s = 0.0;
    for (int i = 0; i < B; ++i)
      s += __hip_atomic_load(&p.P1[i * 20 + tid], __ATOMIC_RELAXED,
                             __HIP_MEMORY_SCOPE_AGENT);
    dtot[tid] = s;
  }
  __syncthreads();
  if (tid < 10) {
    double mean = dtot[tid] * (1.0 / 32768.0);
    double var  = dtot[10 + tid] * (1.0 / 32768.0) - mean * mean;
    stM[tid] = (float)mean;
    stI[tid] = (float)(1.0 / sqrt(var + 1e-5));
  }
  __syncthreads();

  // ---------------- S2: x = tanh(bn(pre1)); qkv stats ON THE FLY (no carry)
  float xa[H], xb[H];
#pragma unroll
  for (int j = 0; j < H; ++j) {
    xa[j] = tanhf(wlds[GI + j] * (p1a[j] - stM[j]) * stI[j] + wlds[BEI + j]);
    xb[j] = tanhf(wlds[GI + j] * (p1b[j] - stM[j]) * stI[j] + wlds[BEI + j]);
  }
  // p1a/p1b dead; only xa/xb (20 floats) persist across the next barrier.
#pragma unroll
  for (int h = 0; h < H; ++h) {
    float qa = 0.f, qb = 0.f, ka = 0.f, kb = 0.f, va = 0.f, vb = 0.f;
#pragma unroll
    for (int j = 0; j < H; ++j) {
      float wq = wlds[WQ + h * H + j], wk = wlds[WK + h * H + j],
            wv = wlds[WV + h * H + j];
      qa = fmaf(xa[j], wq, qa); qb = fmaf(xb[j], wq, qb);
      ka = fmaf(xa[j], wk, ka); kb = fmaf(xb[j], wk, kb);
      va = fmaf(xa[j], wv, va); vb = fmaf(xb[j], wv, vb);
    }
    float r1 = wred(qa + qb), r2 = wred(qa * qa + qb * qb);
    float r3 = wred(ka + kb), r4 = wred(ka * ka + kb * kb);
    float r5 = wred(va + vb), r6 = wred(va * va + vb * vb);
    if (lane == 0) {
      swred[wid * 60 + h]      = r1; swred[wid * 60 + 30 + h] = r2;
      swred[wid * 60 + 10 + h] = r3; swred[wid * 60 + 40 + h] = r4;
      swred[wid * 60 + 20 + h] = r5; swred[wid * 60 + 50 + h] = r6;
    }
  }
  __syncthreads();
  if (tid < 60) {
    double s = 0.0;
#pragma unroll
    for (int w = 0; w < 8; ++w) s += (double)swred[w * 60 + tid];
    __hip_atomic_store(&p.P2[b * 60 + tid], s, __ATOMIC_RELAXED,
                       __HIP_MEMORY_SCOPE_AGENT);
  }
  gbar(p.cnt, 1, tid);
  if (tid < 60) {
    double s = 0.0;
    for (int i = 0; i < B; ++i)
      s += __hip_atomic_load(&p.P2[i * 60 + tid], __ATOMIC_RELAXED,
                             __HIP_MEMORY_SCOPE_AGENT);
    dtot[tid] = s;
  }
  __syncthreads();
  if (tid < 30) {
    double mean = dtot[tid] * (1.0 / 32768.0);
    double var  = dtot[30 + tid] * (1.0 / 32768.0) - mean * mean;
    stM[tid] = (float)mean;
    stI[tid] = (float)(1.0 / sqrt(var + 1e-5));
  }
  __syncthreads();

  // ---------------- S3: recompute qkv pre-acts -> activations; per-b M
  float qva[H], qvb[H], kxa[H], kxb[H], vxa[H], vxb[H];
#pragma unroll
  for (int h = 0; h < H; ++h) {
    float qa = 0.f, qb = 0.f, ka = 0.f, kb = 0.f, va = 0.f, vb = 0.f;
#pragma unroll
    for (int j = 0; j < H; ++j) {
      float wq = wlds[WQ + h * H + j], wk = wlds[WK + h * H + j],
            wv = wlds[WV + h * H + j];
      qa = fmaf(xa[j], wq, qa); qb = fmaf(xb[j], wq, qb);
      ka = fmaf(xa[j], wk, ka); kb = fmaf(xb[j], wk, kb);
      va = fmaf(xa[j], wv, va); vb = fmaf(xb[j], wv, vb);
    }
    qva[h] = fmaxf(wlds[GQ + h] * (qa - stM[h])      * stI[h]      + wlds[BEQ + h], 0.f);
    qvb[h] = fmaxf(wlds[GQ + h] * (qb - stM[h])      * stI[h]      + wlds[BEQ + h], 0.f);
    kxa[h] = fmaxf(wlds[GK + h] * (ka - stM[10 + h]) * stI[10 + h] + wlds[BEK + h], 0.f);
    kxb[h] = fmaxf(wlds[GK + h] * (kb - stM[10 + h]) * stI[10 + h] + wlds[BEK + h], 0.f);
    vxa[h] = tanhf(wlds[GV + h] * (va - stM[20 + h]) * stI[20 + h] + wlds[BEV + h]);
    vxb[h] = tanhf(wlds[GV + h] * (vb - stM[20 + h]) * stI[20 + h] + wlds[BEV + h]);
  }
  // xa/xb dead. M partials, fully unrolled (no runtime private indexing).
#pragma unroll
  for (int i = 0; i < H; ++i)
#pragma unroll
    for (int j = 0; j < H; ++j) {
      float r = wred(kxa[i] * vxa[j] + kxb[i] * vxb[j]);
      if (lane == 0) mpw[wid * 100 + i * 10 + j] = r;
    }
  __syncthreads();
  if (tid < 100) {
    float s = 0.f;
#pragma unroll
    for (int w = 0; w < 8; ++w) s += mpw[w * 100 + tid];
    Ms[tid] = s;
  }
  __syncthreads();

  // ---------------- S4: N = (M Wc^T)/H, prec = q . N
  if (tid < 100) {
    int i = tid / 10, h = tid % 10;
    float a = 0.f;
#pragma unroll
    for (int j = 0; j < H; ++j) a = fmaf(Ms[i * 10 + j], wlds[WC + h * H + j], a);
    Nl[tid] = a * 0.1f;
  }
  __syncthreads();
  float pca[H], pcb[H];
#pragma unroll
  for (int h = 0; h < H; ++h) {
    float a = 0.f, c = 0.f;
#pragma unroll
    for (int i = 0; i < H; ++i) {
      a = fmaf(qva[i], Nl[i * 10 + h], a);
      c = fmaf(qvb[i], Nl[i * 10 + h], c);
    }
    pca[h] = a; pcb[h] = c;
  }
#pragma unroll
  for (int h = 0; h < H; ++h) {
    float r1 = wred(pca[h] + pcb[h]);
    float r2 = wred(pca[h] * pca[h] + pcb[h] * pcb[h]);
    if (lane == 0) { swred[wid * 60 + h] = r1; swred[wid * 60 + 10 + h] = r2; }
  }
  __syncthreads();
  if (tid < 20) {
    double s = 0.0;
#pragma unroll
    for (int w = 0; w < 8; ++w) s += (double)swred[w * 60 + tid];
    __hip_atomic_store(&p.P3[b * 20 + tid], s, __ATOMIC_RELAXED,
                       __HIP_MEMORY_SCOPE_AGENT);
  }
  gbar(p.cnt, 2, tid);
  if (tid < 20) {
    double s = 0.0;
    for (int i = 0; i < B; ++i)
      s += __hip_atomic_load(&p.P3[i * 20 + tid], __ATOMIC_RELAXED,
                             __HIP_MEMORY_SCOPE_AGENT);
    dtot[tid] = s;
  }
  __syncthreads();
  if (tid < 10) {
    double mean = dtot[tid] * (1.0 / 32768.0);
    double var  = dtot[10 + tid] * (1.0 / 32768.0) - mean * mean;
    stM[tid] = (float)mean;
    stI[tid] = (float)(1.0 / sqrt(var + 1e-5));
  }
  __syncthreads();   // all slab-scratch reads done before S5 overwrites

  // ---------------- S5: bn+relu, Iin into LDS slab (stride 11); f32 g-table
  {
    float ca[H], cb[H];
#pragma unroll
    for (int j = 0; j < H; ++j) {
      ca[j] = fmaxf(wlds[GC + j] * (pca[j] - stM[j]) * stI[j] + wlds[BEC + j], 0.f);
      cb[j] = fmaxf(wlds[GC + j] * (pcb[j] - stM[j]) * stI[j] + wlds[BEC + j], 0.f);
    }
#pragma unroll
    for (int h = 0; h < H; ++h) {
      float a = 0.f, c = 0.f;
#pragma unroll
      for (int j = 0; j < H; ++j) {
        float w = wlds[WIN + h * H + j];
        a = fmaf(ca[j], w, a);
        c = fmaf(cb[j], w, c);
      }
      slab[t0 * 11 + h] = a;
      slab[t1 * 11 + h] = c;
    }
    // g[t] = (9(1-0.9^{T-t}) - 4(1-0.8^{T-t})) / T
    const float L2A = -0.15200309344504995f;   // log2(0.9)
    const float L2D = -0.32192809488736235f;   // log2(0.8)
    float m0 = (float)(T - t0), m1 = (float)(T - t1);
    gtab[t0] = (9.0f * (1.0f - exp2f(m0 * L2A)) -
                4.0f * (1.0f - exp2f(m0 * L2D))) * (1.0f / (float)T);
    gtab[t1] = (9.0f * (1.0f - exp2f(m1 * L2A)) -
                4.0f * (1.0f - exp2f(m1 * L2D))) * (1.0f / (float)T);
  }
  __syncthreads();

  // ---------------- S6: LSNN scan, wave 0 only, from LDS
  if (tid < 64) {
    float gs = 0.f;
#pragma unroll
    for (int i = 0; i < 16; ++i) gs += gtab[lane + 64 * i];
    float gtot = __shfl(wred(gs), 0, 64);

    const int slot = lane < H ? lane : 0;   // inactive lanes broadcast slot 0
    float wr[H];
#pragma unroll
    for (int j = 0; j < H; ++j)
      wr[j] = (lane < H) ? p.W_rec[lane * H + j] : 0.f;

    float cur = 0.f, vm = 0.f, S = 0.f;
    unsigned zm = 0u;

    auto step = [&](float iin, float gt) {
      float p01 = (((zm >> 0) & 1u) ? wr[0] : 0.f) + (((zm >> 1) & 1u) ? wr[1] : 0.f);
      float p23 = (((zm >> 2) & 1u) ? wr[2] : 0.f) + (((zm >> 3) & 1u) ? wr[3] : 0.f);
      float p45 = (((zm >> 4) & 1u) ? wr[4] : 0.f) + (((zm >> 5) & 1u) ? wr[5] : 0.f);
      float p67 = (((zm >> 6) & 1u) ? wr[6] : 0.f) + (((zm >> 7) & 1u) ? wr[7] : 0.f);
      float p89 = (((zm >> 8) & 1u) ? wr[8] : 0.f) + (((zm >> 9) & 1u) ? wr[9] : 0.f);
      float rec = ((p01 + p23) + (p45 + p67)) + p89;
      float i_jump = (cur + iin) + rec;
      float v_dec = fmaf(0.1f, i_jump - vm, vm);  // vm + 0.1*(i_jump - vm)
      cur = 0.8f * i_jump;                        // i_dec
      bool z = v_dec > 0.5f;
      vm = z ? 0.f : v_dec;
      S += z ? gt : 0.f;
      zm = (unsigned)__ballot(z) & 0x3FFu;
    };

    float ibuf[8];
#pragma unroll
    for (int u = 0; u < 8; ++u) ibuf[u] = slab[u * 11 + slot];
    float4 gA = *(const float4*)&gtab[0], gB = *(const float4*)&gtab[4];

    for (int t8 = 0; t8 < T - 8; t8 += 8) {
      float4 nA = *(const float4*)&gtab[t8 + 8];
      float4 nB = *(const float4*)&gtab[t8 + 12];
      step(ibuf[0], gA.x); ibuf[0] = slab[(t8 +  8) * 11 + slot];
      step(ibuf[1], gA.y); ibuf[1] = slab[(t8 +  9) * 11 + slot];
      step(ibuf[2], gA.z); ibuf[2] = slab[(t8 + 10) * 11 + slot];
      step(ibuf[3], gA.w); ibuf[3] = slab[(t8 + 11) * 11 + slot];
      step(ibuf[4], gB.x); ibuf[4] = slab[(t8 + 12) * 11 + slot];
      step(ibuf[5], gB.y); ibuf[5] = slab[(t8 + 13) * 11 + slot];
      step(ibuf[6], gB.z); ibuf[6] = slab[(t8 + 14) * 11 + slot];
      step(ibuf[7], gB.w); ibuf[7] = slab[(t8 + 15) * 11 + slot];
      gA = nA; gB = nB;
    }
    step(ibuf[0], gA.x); step(ibuf[1], gA.y);
    step(ibuf[2], gA.z); step(ibuf[3], gA.w);
    step(ibuf[4], gB.x); step(ibuf[5], gB.y);
    step(ibuf[6], gB.z); step(ibuf[7], gB.w);

    int li = lane < H ? lane : 0;
    float c0 = (lane < H) ? S * p.W_cls[li]     : 0.f;
    float c1 = (lane < H) ? S * p.W_cls[H + li] : 0.f;
    float r0 = wred(c0), r1 = wred(c1);
    if (lane == 0) {
      p.out[b * 2 + 0] = r0 + gtot * p.b_cls[0];
      p.out[b * 2 + 1] = r1 + gtot * p.b_cls[1];
    }
  }
}

extern "C" void kernel_launch(void* const* d_in, const int* in_sizes, int n_in,
                              void* d_out, int out_size, void* d_ws, size_t ws_size,
                              hipStream_t stream) {
  Params p;
  p.beeg  = (const float*)d_in[2];
  p.W_ef  = (const float*)d_in[4];
  p.b_ef  = (const float*)d_in[5];
  p.g_i   = (const float*)d_in[6];
  p.be_i  = (const float*)d_in[7];
  p.Wq    = (const float*)d_in[8];
  p.g_q   = (const float*)d_in[9];
  p.be_q  = (const float*)d_in[10];
  p.Wk    = (const float*)d_in[11];
  p.g_k   = (const float*)d_in[12];
  p.be_k  = (const float*)d_in[13];
  p.Wv    = (const float*)d_in[14];
  p.g_v   = (const float*)d_in[15];
  p.be_v  = (const float*)d_in[16];
  p.Wc    = (const float*)d_in[17];
  p.g_c   = (const float*)d_in[18];
  p.be_c  = (const float*)d_in[19];
  p.W_in  = (const float*)d_in[20];
  p.W_rec = (const float*)d_in[21];
  p.W_cls = (const float*)d_in[22];
  p.b_cls = (const float*)d_in[23];

  char* ws = (char*)d_ws;
  p.cnt = (int*)ws;                            // 3 counters, memset below
  p.P1  = (double*)(ws + 256);                 // 32*20 doubles
  p.P2  = (double*)(ws + 256 + 5120);          // 32*60 doubles
  p.P3  = (double*)(ws + 256 + 5120 + 15360);  // 32*20 doubles
  p.out = (float*)d_out;

  hipMemsetAsync(d_ws, 0, 256, stream);   // zero barrier counters (capturable)
  fused5<<<dim3(B), dim3(NT), 0, stream>>>(p);
}